// Round 1
// baseline (544.437 us; speedup 1.0000x reference)
//
#include <hip/hip_runtime.h>
#include <cstdint>
#include <cstddef>

// Problem constants
#define B_   8
#define LQ_  2048
#define LK_  2048
#define DQ_  1024
#define DK_  1024
#define DV_  1024

typedef __attribute__((ext_vector_type(8))) __bf16 bf16x8;
typedef __attribute__((ext_vector_type(4))) float f32x4;
typedef __attribute__((ext_vector_type(8))) unsigned short ushortx8;

__device__ __forceinline__ unsigned short f2bf(float f) {
  unsigned u = __builtin_bit_cast(unsigned, f);
  u = u + 0x7fffu + ((u >> 16) & 1u);  // round-to-nearest-even
  return (unsigned short)(u >> 16);
}
__device__ __forceinline__ float bf2f(unsigned short h) {
  unsigned u = ((unsigned)h) << 16;
  return __builtin_bit_cast(float, u);
}

__device__ __forceinline__ void gld_lds16(const void* g, void* l) {
  __builtin_amdgcn_global_load_lds((__attribute__((address_space(1))) void*)(void*)g,
                                   (__attribute__((address_space(3))) void*)l, 16, 0, 0);
}

// ---------------- transpose + cast: fp32 [R][C] -> bf16 [C][R] ----------------
__global__ __launch_bounds__(256) void transpose_cast_kernel(
    const float* __restrict__ in, unsigned short* __restrict__ out,
    int R, int C, long in_bstride, long out_bstride) {
  __shared__ float t[32][33];
  const float* inb = in + (size_t)blockIdx.z * in_bstride;
  unsigned short* outb = out + (size_t)blockIdx.z * out_bstride;
  int c0 = blockIdx.x * 32, r0 = blockIdx.y * 32;
  int tx = threadIdx.x, ty = threadIdx.y;  // block (32,8)
#pragma unroll
  for (int k = 0; k < 4; ++k) {
    int r = ty + k * 8;
    t[r][tx] = inb[(size_t)(r0 + r) * C + c0 + tx];
  }
  __syncthreads();
#pragma unroll
  for (int k = 0; k < 4; ++k) {
    int c = ty + k * 8;
    outb[(size_t)(c0 + c) * R + r0 + tx] = f2bf(t[tx][c]);
  }
}

// ---------------- GEMM: C[M,N] = A[M,K] @ Bt[N,K]^T  (m97 structure) ----------------
// AF32/BF32: operand is fp32 in global (inline cast while staging to LDS), else bf16 (async global_load_lds)
// OUTM: 0 = store bf16, 1 = store bf16 scaled, 2 = store fp32
template <int AF32, int BF32, int OUTM>
__global__ __launch_bounds__(256) void gemm_bt_kernel(
    const void* __restrict__ Ap, const void* __restrict__ Bp, void* __restrict__ Cp,
    int M, int N, int K, long a_bstride, long b_bstride, long c_bstride, float scale) {
  __shared__ unsigned short lA[128 * 32];
  __shared__ unsigned short lB[128 * 32];

  const int tid = threadIdx.x;
  const int wave = tid >> 6;
  const int lane = tid & 63;
  const int lane15 = lane & 15;
  const int lhalf = lane >> 4;
  const int m0 = blockIdx.x * 128;
  const int n0 = blockIdx.y * 128;
  const int wm = (wave & 1) * 64;
  const int wn = (wave >> 1) * 64;

  const size_t boffA = (size_t)blockIdx.z * a_bstride;
  const size_t boffB = (size_t)blockIdx.z * b_bstride;
  const size_t boffC = (size_t)blockIdx.z * c_bstride;

  f32x4 acc[4][4];
#pragma unroll
  for (int i = 0; i < 4; ++i)
#pragma unroll
    for (int j = 0; j < 4; ++j)
      acc[i][j] = (f32x4){0.f, 0.f, 0.f, 0.f};

  for (int k0 = 0; k0 < K; k0 += 32) {
    // ---- stage A tile (128 x 32) ----
    if constexpr (AF32) {
      const float* Af = (const float*)Ap + boffA;
#pragma unroll
      for (int it = 0; it < 4; ++it) {
        int e = (it * 256 + tid) * 4;
        int r = e >> 5, c = e & 31;
        const float4 v = *(const float4*)(Af + (size_t)(m0 + r) * K + (k0 + c));
        ushort4 h;
        h.x = f2bf(v.x); h.y = f2bf(v.y); h.z = f2bf(v.z); h.w = f2bf(v.w);
        *(ushort4*)&lA[e] = h;
      }
    } else {
      const unsigned short* Ab = (const unsigned short*)Ap + boffA;
#pragma unroll
      for (int j = 0; j < 2; ++j) {
        int e = (wave * 2 + j) * 512 + lane * 8;
        int r = e >> 5, c = e & 31;
        gld_lds16(Ab + (size_t)(m0 + r) * K + (k0 + c), &lA[e]);
      }
    }
    // ---- stage B tile (128 x 32) ----
    if constexpr (BF32) {
      const float* Bf = (const float*)Bp + boffB;
#pragma unroll
      for (int it = 0; it < 4; ++it) {
        int e = (it * 256 + tid) * 4;
        int r = e >> 5, c = e & 31;
        const float4 v = *(const float4*)(Bf + (size_t)(n0 + r) * K + (k0 + c));
        ushort4 h;
        h.x = f2bf(v.x); h.y = f2bf(v.y); h.z = f2bf(v.z); h.w = f2bf(v.w);
        *(ushort4*)&lB[e] = h;
      }
    } else {
      const unsigned short* Bb = (const unsigned short*)Bp + boffB;
#pragma unroll
      for (int j = 0; j < 2; ++j) {
        int e = (wave * 2 + j) * 512 + lane * 8;
        int r = e >> 5, c = e & 31;
        gld_lds16(Bb + (size_t)(n0 + r) * K + (k0 + c), &lB[e]);
      }
    }
    __syncthreads();

    bf16x8 af[4], bfr[4];
#pragma unroll
    for (int i = 0; i < 4; ++i)
      af[i] = *(const bf16x8*)&lA[(wm + i * 16 + lane15) * 32 + lhalf * 8];
#pragma unroll
    for (int j = 0; j < 4; ++j)
      bfr[j] = *(const bf16x8*)&lB[(wn + j * 16 + lane15) * 32 + lhalf * 8];
#pragma unroll
    for (int i = 0; i < 4; ++i)
#pragma unroll
      for (int j = 0; j < 4; ++j)
        acc[i][j] = __builtin_amdgcn_mfma_f32_16x16x32_bf16(af[i], bfr[j], acc[i][j], 0, 0, 0);
    __syncthreads();
  }

  // ---- epilogue: C/D layout col=lane&15, row=(lane>>4)*4+reg ----
#pragma unroll
  for (int i = 0; i < 4; ++i) {
    int row = m0 + wm + i * 16 + lhalf * 4;
#pragma unroll
    for (int j = 0; j < 4; ++j) {
      int col = n0 + wn + j * 16 + lane15;
#pragma unroll
      for (int r = 0; r < 4; ++r) {
        float v = acc[i][j][r];
        if constexpr (OUTM == 0) {
          ((unsigned short*)Cp + boffC)[(size_t)(row + r) * N + col] = f2bf(v);
        } else if constexpr (OUTM == 1) {
          ((unsigned short*)Cp + boffC)[(size_t)(row + r) * N + col] = f2bf(v * scale);
        } else {
          ((float*)Cp + boffC)[(size_t)(row + r) * N + col] = v;
        }
      }
    }
  }
}

// ---------------- row softmax with valid_len masking, in-place on bf16 scores ----------------
__global__ __launch_bounds__(256) void softmax_kernel(unsigned short* __restrict__ scores,
                                                      const int* __restrict__ valid_lens) {
  const int row = blockIdx.x;
  const int b = row >> 11;  // LQ = 2048
  const int vl = valid_lens[b];
  unsigned short* rp = scores + (size_t)row * LK_;
  const int tid = threadIdx.x;
  const int wid = tid >> 6, lane = tid & 63;
  __shared__ float sred[4];

  const int cb = tid * 8;
  ushortx8 h = *(const ushortx8*)(rp + cb);
  float x[8];
#pragma unroll
  for (int t = 0; t < 8; ++t) x[t] = bf2f(h[t]);

  float m = -3.4e38f;
#pragma unroll
  for (int t = 0; t < 8; ++t)
    if (cb + t < vl) m = fmaxf(m, x[t]);
#pragma unroll
  for (int off = 32; off >= 1; off >>= 1) m = fmaxf(m, __shfl_xor(m, off));
  if (lane == 0) sred[wid] = m;
  __syncthreads();
  m = fmaxf(fmaxf(sred[0], sred[1]), fmaxf(sred[2], sred[3]));
  __syncthreads();

  float e[8];
  float s = 0.f;
#pragma unroll
  for (int t = 0; t < 8; ++t) {
    e[t] = (cb + t < vl) ? __expf(x[t] - m) : 0.f;
    s += e[t];
  }
#pragma unroll
  for (int off = 32; off >= 1; off >>= 1) s += __shfl_xor(s, off);
  if (lane == 0) sred[wid] = s;
  __syncthreads();
  s = sred[0] + sred[1] + sred[2] + sred[3];
  float inv = 1.f / s;

  ushortx8 o;
#pragma unroll
  for (int t = 0; t < 8; ++t) o[t] = f2bf(e[t] * inv);
  *(ushortx8*)(rp + cb) = o;
}

extern "C" void kernel_launch(void* const* d_in, const int* in_sizes, int n_in,
                              void* d_out, int out_size, void* d_ws, size_t ws_size,
                              hipStream_t stream) {
  const float* queries = (const float*)d_in[0];    // [8,2048,1024]
  const float* keys = (const float*)d_in[1];       // [8,2048,1024]
  const float* values = (const float*)d_in[2];     // [8,2048,1024]
  const int* valid_lens = (const int*)d_in[3];     // [8]
  const float* W_q = (const float*)d_in[4];        // [1024,1024]
  float* out = (float*)d_out;                      // [8,2048,1024] fp32

  // ws layout (ushort elements): q 16M | scores 32M | valsT 16M | WqT 1M  => 130 MiB
  unsigned short* ws = (unsigned short*)d_ws;
  unsigned short* q_bf = ws;
  unsigned short* scores = ws + (size_t)16 * 1024 * 1024;
  unsigned short* valsT = scores + (size_t)32 * 1024 * 1024;
  unsigned short* wqT = valsT + (size_t)16 * 1024 * 1024;

  // 1) WqT[k][d] = W_q[d][k]  (bf16)
  transpose_cast_kernel<<<dim3(32, 32, 1), dim3(32, 8), 0, stream>>>(
      W_q, wqT, 1024, 1024, 0, 0);
  // 2) valsT[b][v][s] = values[b][s][v]  (bf16)
  transpose_cast_kernel<<<dim3(32, 64, 8), dim3(32, 8), 0, stream>>>(
      values, valsT, 2048, 1024, (long)2048 * 1024, (long)1024 * 2048);
  // 3) q = queries @ W_q  -> bf16 [16384,1024]
  gemm_bt_kernel<1, 0, 0><<<dim3(128, 8, 1), 256, 0, stream>>>(
      queries, wqT, q_bf, 16384, 1024, 1024, 0, 0, 0, 1.f);
  // 4) scores = q @ keys^T / 32 -> bf16 [8][2048][2048]
  gemm_bt_kernel<0, 1, 1><<<dim3(16, 16, 8), 256, 0, stream>>>(
      q_bf, keys, scores, 2048, 2048, 1024,
      (long)2048 * 1024, (long)2048 * 1024, (long)2048 * 2048, 0.03125f);
  // 5) softmax rows (masked by valid_lens), in place
  softmax_kernel<<<dim3(B_ * LQ_), 256, 0, stream>>>(scores, valid_lens);
  // 6) out = attn @ values  (fp32 epilogue)
  gemm_bt_kernel<0, 0, 2><<<dim3(16, 8, 8), 256, 0, stream>>>(
      scores, valsT, out, 2048, 1024, 2048,
      (long)2048 * 2048, (long)1024 * 2048, (long)2048 * 1024, 1.f);
}

// Round 2
// 495.480 us; speedup vs baseline: 1.0988x; 1.0988x over previous
//
#include <hip/hip_runtime.h>
#include <cstdint>
#include <cstddef>

#define B_   8
#define LQ_  2048
#define LK_  2048

typedef __attribute__((ext_vector_type(8))) __bf16 bf16x8;
typedef __attribute__((ext_vector_type(4))) float f32x4;
typedef __attribute__((ext_vector_type(8))) unsigned short ushortx8;

__device__ __forceinline__ unsigned short f2bf(float f) {
  unsigned u = __builtin_bit_cast(unsigned, f);
  u = u + 0x7fffu + ((u >> 16) & 1u);  // round-to-nearest-even
  return (unsigned short)(u >> 16);
}
__device__ __forceinline__ float bf2f(unsigned short h) {
  unsigned u = ((unsigned)h) << 16;
  return __builtin_bit_cast(float, u);
}

__device__ __forceinline__ void gld_lds16(const void* g, void* l) {
  __builtin_amdgcn_global_load_lds((__attribute__((address_space(1))) void*)(void*)g,
                                   (__attribute__((address_space(3))) void*)l, 16, 0, 0);
}

// ---------------- flat cast fp32 -> bf16, 8 elems/thread ----------------
__global__ __launch_bounds__(256) void cast_bf16_kernel(
    const float* __restrict__ in, unsigned short* __restrict__ out) {
  size_t i = ((size_t)blockIdx.x * 256 + threadIdx.x) * 8;
  float4 a = *(const float4*)(in + i);
  float4 b = *(const float4*)(in + i + 4);
  ushortx8 o;
  o[0] = f2bf(a.x); o[1] = f2bf(a.y); o[2] = f2bf(a.z); o[3] = f2bf(a.w);
  o[4] = f2bf(b.x); o[5] = f2bf(b.y); o[6] = f2bf(b.z); o[7] = f2bf(b.w);
  *(ushortx8*)(out + i) = o;
}

// ---------------- transpose + cast: fp32 [R][C] -> bf16 [C][R] ----------------
__global__ __launch_bounds__(256) void transpose_cast_kernel(
    const float* __restrict__ in, unsigned short* __restrict__ out,
    int R, int C, long in_bstride, long out_bstride) {
  __shared__ float t[32][33];
  const float* inb = in + (size_t)blockIdx.z * in_bstride;
  unsigned short* outb = out + (size_t)blockIdx.z * out_bstride;
  int c0 = blockIdx.x * 32, r0 = blockIdx.y * 32;
  int tx = threadIdx.x, ty = threadIdx.y;  // block (32,8)
#pragma unroll
  for (int k = 0; k < 4; ++k) {
    int r = ty + k * 8;
    t[r][tx] = inb[(size_t)(r0 + r) * C + c0 + tx];
  }
  __syncthreads();
#pragma unroll
  for (int k = 0; k < 4; ++k) {
    int c = ty + k * 8;
    outb[(size_t)(c0 + c) * R + r0 + tx] = f2bf(t[tx][c]);
  }
}

// ---------------- GEMM: C[M,N] = A[M,K] @ Bt[N,K]^T  (m97 structure, bf16 operands) ----
// LDS layout XOR-swizzled at 16B granularity: logical (row, col_block cb in 0..3)
// stored at position cb ^ ((row>>1)&3). global_load_lds lds-dst is forced to
// base+lane*16, so the swizzle is inverted on the global source address.
// OUTM: 0 = store bf16, 1 = store bf16 scaled, 2 = store fp32
template <int OUTM>
__global__ __launch_bounds__(256) void gemm_bt_kernel(
    const unsigned short* __restrict__ A, const unsigned short* __restrict__ B,
    void* __restrict__ Cp, int M, int N, int K,
    long a_bstride, long b_bstride, long c_bstride, float scale) {
  __shared__ unsigned short lA[128 * 32];
  __shared__ unsigned short lB[128 * 32];

  const int tid = threadIdx.x;
  const int wave = tid >> 6;
  const int lane = tid & 63;
  const int lane15 = lane & 15;
  const int lhalf = lane >> 4;
  const int m0 = blockIdx.x * 128;
  const int n0 = blockIdx.y * 128;
  const int wm = (wave & 1) * 64;
  const int wn = (wave >> 1) * 64;

  const unsigned short* Ab = A + (size_t)blockIdx.z * a_bstride;
  const unsigned short* Bb = B + (size_t)blockIdx.z * b_bstride;

  // staging: 16B-block index within the 128x32 tile, per wave-instruction
  // blk = wavebase + lane ; row = blk>>2 ; stored col-pos = blk&3
  // logical col_block = pos ^ ((row>>1)&3)
  int sblk0 = (wave * 2 + 0) * 64 + lane;
  int sblk1 = (wave * 2 + 1) * 64 + lane;
  int sr0 = sblk0 >> 2, sc0 = ((sblk0 & 3) ^ ((sr0 >> 1) & 3)) * 8;
  int sr1 = sblk1 >> 2, sc1 = ((sblk1 & 3) ^ ((sr1 >> 1) & 3)) * 8;

  f32x4 acc[4][4];
#pragma unroll
  for (int i = 0; i < 4; ++i)
#pragma unroll
    for (int j = 0; j < 4; ++j)
      acc[i][j] = (f32x4){0.f, 0.f, 0.f, 0.f};

  // fragment-read swizzle: row = w? + i*16 + lane15; (row>>1)&3 is invariant
  // across i (rows differ by 16) — compute once
  const int swzA = ((wm + lane15) >> 1) & 3;
  const int swzB = ((wn + lane15) >> 1) & 3;
  const int rdA = (lhalf ^ swzA) * 8;
  const int rdB = (lhalf ^ swzB) * 8;

  for (int k0 = 0; k0 < K; k0 += 32) {
    gld_lds16(Ab + (size_t)(m0 + sr0) * K + (k0 + sc0), &lA[sblk0 * 8]);
    gld_lds16(Ab + (size_t)(m0 + sr1) * K + (k0 + sc1), &lA[sblk1 * 8]);
    gld_lds16(Bb + (size_t)(n0 + sr0) * K + (k0 + sc0), &lB[sblk0 * 8]);
    gld_lds16(Bb + (size_t)(n0 + sr1) * K + (k0 + sc1), &lB[sblk1 * 8]);
    __syncthreads();

    bf16x8 af[4], bfr[4];
#pragma unroll
    for (int i = 0; i < 4; ++i)
      af[i] = *(const bf16x8*)&lA[(wm + i * 16 + lane15) * 32 + rdA];
#pragma unroll
    for (int j = 0; j < 4; ++j)
      bfr[j] = *(const bf16x8*)&lB[(wn + j * 16 + lane15) * 32 + rdB];
#pragma unroll
    for (int i = 0; i < 4; ++i)
#pragma unroll
      for (int j = 0; j < 4; ++j)
        acc[i][j] = __builtin_amdgcn_mfma_f32_16x16x32_bf16(af[i], bfr[j], acc[i][j], 0, 0, 0);
    __syncthreads();
  }

  // ---- epilogue: C/D layout col=lane&15, row=(lane>>4)*4+reg ----
  const size_t boffC = (size_t)blockIdx.z * c_bstride;
#pragma unroll
  for (int i = 0; i < 4; ++i) {
    int row = m0 + wm + i * 16 + lhalf * 4;
#pragma unroll
    for (int j = 0; j < 4; ++j) {
      int col = n0 + wn + j * 16 + lane15;
#pragma unroll
      for (int r = 0; r < 4; ++r) {
        float v = acc[i][j][r];
        if constexpr (OUTM == 0) {
          ((unsigned short*)Cp + boffC)[(size_t)(row + r) * N + col] = f2bf(v);
        } else if constexpr (OUTM == 1) {
          ((unsigned short*)Cp + boffC)[(size_t)(row + r) * N + col] = f2bf(v * scale);
        } else {
          ((float*)Cp + boffC)[(size_t)(row + r) * N + col] = v;
        }
      }
    }
  }
}

// ---------------- row softmax with valid_len masking, in-place on bf16 scores ----------------
__global__ __launch_bounds__(256) void softmax_kernel(unsigned short* __restrict__ scores,
                                                      const int* __restrict__ valid_lens) {
  const int row = blockIdx.x;
  const int b = row >> 11;  // LQ = 2048
  const int vl = valid_lens[b];
  unsigned short* rp = scores + (size_t)row * LK_;
  const int tid = threadIdx.x;
  const int wid = tid >> 6, lane = tid & 63;
  __shared__ float sred[4];

  const int cb = tid * 8;
  ushortx8 h = *(const ushortx8*)(rp + cb);
  float x[8];
#pragma unroll
  for (int t = 0; t < 8; ++t) x[t] = bf2f(h[t]);

  float m = -3.4e38f;
#pragma unroll
  for (int t = 0; t < 8; ++t)
    if (cb + t < vl) m = fmaxf(m, x[t]);
#pragma unroll
  for (int off = 32; off >= 1; off >>= 1) m = fmaxf(m, __shfl_xor(m, off));
  if (lane == 0) sred[wid] = m;
  __syncthreads();
  m = fmaxf(fmaxf(sred[0], sred[1]), fmaxf(sred[2], sred[3]));
  __syncthreads();

  float e[8];
  float s = 0.f;
#pragma unroll
  for (int t = 0; t < 8; ++t) {
    e[t] = (cb + t < vl) ? __expf(x[t] - m) : 0.f;
    s += e[t];
  }
#pragma unroll
  for (int off = 32; off >= 1; off >>= 1) s += __shfl_xor(s, off);
  if (lane == 0) sred[wid] = s;
  __syncthreads();
  s = sred[0] + sred[1] + sred[2] + sred[3];
  float inv = 1.f / s;

  ushortx8 o;
#pragma unroll
  for (int t = 0; t < 8; ++t) o[t] = f2bf(e[t] * inv);
  *(ushortx8*)(rp + cb) = o;
}

extern "C" void kernel_launch(void* const* d_in, const int* in_sizes, int n_in,
                              void* d_out, int out_size, void* d_ws, size_t ws_size,
                              hipStream_t stream) {
  const float* queries = (const float*)d_in[0];    // [8,2048,1024]
  const float* keys = (const float*)d_in[1];       // [8,2048,1024]
  const float* values = (const float*)d_in[2];     // [8,2048,1024]
  const int* valid_lens = (const int*)d_in[3];     // [8]
  const float* W_q = (const float*)d_in[4];        // [1024,1024]
  float* out = (float*)d_out;                      // [8,2048,1024] fp32

  // ws layout (ushort elems):
  //   q_bf    [0, 16M)
  //   scores  [16M, 48M)   (qry_bf aliases this region — dead before GEMM2)
  //   valsT   [48M, 64M)
  //   wqT     [64M, 65M)
  //   keys_bf [65M, 81M)        total 162 MiB
  unsigned short* ws = (unsigned short*)d_ws;
  const size_t M1 = (size_t)1024 * 1024;
  unsigned short* q_bf = ws;
  unsigned short* scores = ws + 16 * M1;
  unsigned short* qry_bf = scores;  // alias
  unsigned short* valsT = ws + 48 * M1;
  unsigned short* wqT = ws + 64 * M1;
  unsigned short* keys_bf = ws + 65 * M1;

  // casts: 16M elems each -> 8192 blocks of 256 threads (8 elems/thread)
  cast_bf16_kernel<<<dim3(8192), 256, 0, stream>>>(queries, qry_bf);
  cast_bf16_kernel<<<dim3(8192), 256, 0, stream>>>(keys, keys_bf);
  // WqT[k][d] = W_q[d][k]  (bf16)
  transpose_cast_kernel<<<dim3(32, 32, 1), dim3(32, 8), 0, stream>>>(
      W_q, wqT, 1024, 1024, 0, 0);
  // valsT[b][v][s] = values[b][s][v]  (bf16)
  transpose_cast_kernel<<<dim3(32, 64, 8), dim3(32, 8), 0, stream>>>(
      values, valsT, 2048, 1024, (long)2048 * 1024, (long)1024 * 2048);
  // GEMM1: q = queries @ W_q -> bf16 [16384,1024]
  gemm_bt_kernel<0><<<dim3(128, 8, 1), 256, 0, stream>>>(
      qry_bf, wqT, q_bf, 16384, 1024, 1024, 0, 0, 0, 1.f);
  // GEMM2: scores = q @ keys^T / 32 -> bf16 [8][2048][2048]
  gemm_bt_kernel<1><<<dim3(16, 16, 8), 256, 0, stream>>>(
      q_bf, keys_bf, scores, 2048, 2048, 1024,
      (long)2048 * 1024, (long)2048 * 1024, (long)2048 * 2048, 0.03125f);
  // softmax rows (masked by valid_lens), in place
  softmax_kernel<<<dim3(B_ * LQ_), 256, 0, stream>>>(scores, valid_lens);
  // GEMM3: out = attn @ values (fp32 epilogue)
  gemm_bt_kernel<2><<<dim3(16, 8, 8), 256, 0, stream>>>(
      scores, valsT, out, 2048, 1024, 2048,
      (long)2048 * 2048, (long)1024 * 2048, (long)2048 * 1024, 1.f);
}

// Round 3
// 473.190 us; speedup vs baseline: 1.1506x; 1.0471x over previous
//
#include <hip/hip_runtime.h>
#include <cstdint>
#include <cstddef>

#define B_   8
#define LQ_  2048
#define LK_  2048

typedef __attribute__((ext_vector_type(8))) __bf16 bf16x8;
typedef __attribute__((ext_vector_type(4))) float f32x4;
typedef __attribute__((ext_vector_type(8))) unsigned short ushortx8;

__device__ __forceinline__ unsigned short f2bf(float f) {
  unsigned u = __builtin_bit_cast(unsigned, f);
  u = u + 0x7fffu + ((u >> 16) & 1u);  // round-to-nearest-even
  return (unsigned short)(u >> 16);
}
__device__ __forceinline__ float bf2f(unsigned short h) {
  unsigned u = ((unsigned)h) << 16;
  return __builtin_bit_cast(float, u);
}

__device__ __forceinline__ void gld_lds16(const void* g, void* l) {
  __builtin_amdgcn_global_load_lds((__attribute__((address_space(1))) void*)(void*)g,
                                   (__attribute__((address_space(3))) void*)l, 16, 0, 0);
}

// ---------------- flat cast fp32 -> bf16, 8 elems/thread ----------------
__global__ __launch_bounds__(256) void cast_bf16_kernel(
    const float* __restrict__ in, unsigned short* __restrict__ out) {
  size_t i = ((size_t)blockIdx.x * 256 + threadIdx.x) * 8;
  float4 a = *(const float4*)(in + i);
  float4 b = *(const float4*)(in + i + 4);
  ushortx8 o;
  o[0] = f2bf(a.x); o[1] = f2bf(a.y); o[2] = f2bf(a.z); o[3] = f2bf(a.w);
  o[4] = f2bf(b.x); o[5] = f2bf(b.y); o[6] = f2bf(b.z); o[7] = f2bf(b.w);
  *(ushortx8*)(out + i) = o;
}

// ---------------- transpose + cast: fp32 [R][C] -> bf16 [C][R] ----------------
__global__ __launch_bounds__(256) void transpose_cast_kernel(
    const float* __restrict__ in, unsigned short* __restrict__ out,
    int R, int C, long in_bstride, long out_bstride) {
  __shared__ float t[32][33];
  const float* inb = in + (size_t)blockIdx.z * in_bstride;
  unsigned short* outb = out + (size_t)blockIdx.z * out_bstride;
  int c0 = blockIdx.x * 32, r0 = blockIdx.y * 32;
  int tx = threadIdx.x, ty = threadIdx.y;  // block (32,8)
#pragma unroll
  for (int k = 0; k < 4; ++k) {
    int r = ty + k * 8;
    t[r][tx] = inb[(size_t)(r0 + r) * C + c0 + tx];
  }
  __syncthreads();
#pragma unroll
  for (int k = 0; k < 4; ++k) {
    int c = ty + k * 8;
    outb[(size_t)(c0 + c) * R + r0 + tx] = f2bf(t[tx][c]);
  }
}

// ---------------- GEMM: C[M,N] = A[M,K] @ Bt[N,K]^T, BK=64 ----------------
// Grid: (x = batch, y = M-tile, z = N-tile). x-fastest dispatch round-robins
// batches across XCDs -> per-XCD L2 holds one batch's B operand.
// LDS tiles 128x64 bf16, XOR-swizzled at 16B chunks: chunk stored at
// pos = chunk ^ (row & 7). global_load_lds dst is forced base+lane*16, so
// the swizzle is inverted on the global source address.
// OUTM: 0 = store bf16, 1 = store bf16 scaled, 2 = store fp32
template <int OUTM>
__global__ __launch_bounds__(256) void gemm_bt_kernel(
    const unsigned short* __restrict__ A, const unsigned short* __restrict__ B,
    void* __restrict__ Cp, int M, int N, int K,
    long a_bstride, long b_bstride, long c_bstride, float scale) {
  __shared__ unsigned short lA[128 * 64];
  __shared__ unsigned short lB[128 * 64];

  const int tid = threadIdx.x;
  const int wave = tid >> 6;
  const int lane = tid & 63;
  const int lane15 = lane & 15;
  const int lhalf = lane >> 4;
  const int m0 = blockIdx.y * 128;
  const int n0 = blockIdx.z * 128;
  const int wm = (wave & 1) * 64;
  const int wn = (wave >> 1) * 64;

  const unsigned short* Ab = A + (size_t)blockIdx.x * a_bstride;
  const unsigned short* Bb = B + (size_t)blockIdx.x * b_bstride;

  // staging: 1024 16B-chunks per 128x64 tile, 4 per thread per operand.
  // blk = (wave*4 + j)*64 + lane ; row = blk>>3 ; stored pos = blk&7 ;
  // logical chunk c = pos ^ (row&7) ; global col = c*8
  int sr[4], sc[4], sb[4];
#pragma unroll
  for (int j = 0; j < 4; ++j) {
    int blk = (wave * 4 + j) * 64 + lane;
    sb[j] = blk;
    sr[j] = blk >> 3;
    sc[j] = ((blk & 7) ^ ((blk >> 3) & 7)) * 8;
  }

  f32x4 acc[4][4];
#pragma unroll
  for (int i = 0; i < 4; ++i)
#pragma unroll
    for (int j = 0; j < 4; ++j)
      acc[i][j] = (f32x4){0.f, 0.f, 0.f, 0.f};

  // fragment reads: row = w? + i*16 + lane15 -> row&7 = lane15&7 (invariant
  // over i since tiles step by 16). logical chunk = s*4 + lhalf.
  const int rswz = lane15 & 7;

  for (int k0 = 0; k0 < K; k0 += 64) {
#pragma unroll
    for (int j = 0; j < 4; ++j)
      gld_lds16(Ab + (size_t)(m0 + sr[j]) * K + (k0 + sc[j]), &lA[sb[j] * 8]);
#pragma unroll
    for (int j = 0; j < 4; ++j)
      gld_lds16(Bb + (size_t)(n0 + sr[j]) * K + (k0 + sc[j]), &lB[sb[j] * 8]);
    __syncthreads();

#pragma unroll
    for (int s = 0; s < 2; ++s) {
      const int cA = ((s * 4 + lhalf) ^ rswz) * 8;
      bf16x8 af[4], bfr[4];
#pragma unroll
      for (int i = 0; i < 4; ++i)
        af[i] = *(const bf16x8*)&lA[(wm + i * 16 + lane15) * 64 + cA];
#pragma unroll
      for (int j = 0; j < 4; ++j)
        bfr[j] = *(const bf16x8*)&lB[(wn + j * 16 + lane15) * 64 + cA];
#pragma unroll
      for (int i = 0; i < 4; ++i)
#pragma unroll
        for (int j = 0; j < 4; ++j)
          acc[i][j] = __builtin_amdgcn_mfma_f32_16x16x32_bf16(af[i], bfr[j], acc[i][j], 0, 0, 0);
    }
    __syncthreads();
  }

  // ---- epilogue: C/D layout col=lane&15, row=(lane>>4)*4+reg ----
  const size_t boffC = (size_t)blockIdx.x * c_bstride;
#pragma unroll
  for (int i = 0; i < 4; ++i) {
    int row = m0 + wm + i * 16 + lhalf * 4;
#pragma unroll
    for (int j = 0; j < 4; ++j) {
      int col = n0 + wn + j * 16 + lane15;
#pragma unroll
      for (int r = 0; r < 4; ++r) {
        float v = acc[i][j][r];
        if constexpr (OUTM == 0) {
          ((unsigned short*)Cp + boffC)[(size_t)(row + r) * N + col] = f2bf(v);
        } else if constexpr (OUTM == 1) {
          ((unsigned short*)Cp + boffC)[(size_t)(row + r) * N + col] = f2bf(v * scale);
        } else {
          ((float*)Cp + boffC)[(size_t)(row + r) * N + col] = v;
        }
      }
    }
  }
}

// ---------------- row softmax with valid_len masking, in-place on bf16 scores ----------------
__global__ __launch_bounds__(256) void softmax_kernel(unsigned short* __restrict__ scores,
                                                      const int* __restrict__ valid_lens) {
  const int row = blockIdx.x;
  const int b = row >> 11;  // LQ = 2048
  const int vl = valid_lens[b];
  unsigned short* rp = scores + (size_t)row * LK_;
  const int tid = threadIdx.x;
  const int wid = tid >> 6, lane = tid & 63;
  __shared__ float sred[4];

  const int cb = tid * 8;
  ushortx8 h = *(const ushortx8*)(rp + cb);
  float x[8];
#pragma unroll
  for (int t = 0; t < 8; ++t) x[t] = bf2f(h[t]);

  float m = -3.4e38f;
#pragma unroll
  for (int t = 0; t < 8; ++t)
    if (cb + t < vl) m = fmaxf(m, x[t]);
#pragma unroll
  for (int off = 32; off >= 1; off >>= 1) m = fmaxf(m, __shfl_xor(m, off));
  if (lane == 0) sred[wid] = m;
  __syncthreads();
  m = fmaxf(fmaxf(sred[0], sred[1]), fmaxf(sred[2], sred[3]));
  __syncthreads();

  float e[8];
  float s = 0.f;
#pragma unroll
  for (int t = 0; t < 8; ++t) {
    e[t] = (cb + t < vl) ? __expf(x[t] - m) : 0.f;
    s += e[t];
  }
#pragma unroll
  for (int off = 32; off >= 1; off >>= 1) s += __shfl_xor(s, off);
  if (lane == 0) sred[wid] = s;
  __syncthreads();
  s = sred[0] + sred[1] + sred[2] + sred[3];
  float inv = 1.f / s;

  ushortx8 o;
#pragma unroll
  for (int t = 0; t < 8; ++t) o[t] = f2bf(e[t] * inv);
  *(ushortx8*)(rp + cb) = o;
}

extern "C" void kernel_launch(void* const* d_in, const int* in_sizes, int n_in,
                              void* d_out, int out_size, void* d_ws, size_t ws_size,
                              hipStream_t stream) {
  const float* queries = (const float*)d_in[0];    // [8,2048,1024]
  const float* keys = (const float*)d_in[1];       // [8,2048,1024]
  const float* values = (const float*)d_in[2];     // [8,2048,1024]
  const int* valid_lens = (const int*)d_in[3];     // [8]
  const float* W_q = (const float*)d_in[4];        // [1024,1024]
  float* out = (float*)d_out;                      // [8,2048,1024] fp32

  // ws layout (ushort elems):
  //   q_bf    [0, 16M)
  //   scores  [16M, 48M)   (qry_bf aliases this region — dead before GEMM2)
  //   valsT   [48M, 64M)
  //   wqT     [64M, 65M)
  //   keys_bf [65M, 81M)        total 162 MiB
  unsigned short* ws = (unsigned short*)d_ws;
  const size_t M1 = (size_t)1024 * 1024;
  unsigned short* q_bf = ws;
  unsigned short* scores = ws + 16 * M1;
  unsigned short* qry_bf = scores;  // alias
  unsigned short* valsT = ws + 48 * M1;
  unsigned short* wqT = ws + 64 * M1;
  unsigned short* keys_bf = ws + 65 * M1;

  // casts: 16M elems each -> 8192 blocks of 256 threads (8 elems/thread)
  cast_bf16_kernel<<<dim3(8192), 256, 0, stream>>>(queries, qry_bf);
  cast_bf16_kernel<<<dim3(8192), 256, 0, stream>>>(keys, keys_bf);
  // WqT[k][d] = W_q[d][k]  (bf16)
  transpose_cast_kernel<<<dim3(32, 32, 1), dim3(32, 8), 0, stream>>>(
      W_q, wqT, 1024, 1024, 0, 0);
  // valsT[b][v][s] = values[b][s][v]  (bf16)
  transpose_cast_kernel<<<dim3(32, 64, 8), dim3(32, 8), 0, stream>>>(
      values, valsT, 2048, 1024, (long)2048 * 1024, (long)1024 * 2048);
  // GEMM1: q = queries @ W_q -> bf16 [16384,1024]   grid(x=1, y=Mtiles, z=Ntiles)
  gemm_bt_kernel<0><<<dim3(1, 128, 8), 256, 0, stream>>>(
      qry_bf, wqT, q_bf, 16384, 1024, 1024, 0, 0, 0, 1.f);
  // GEMM2: scores = q @ keys^T / 32 -> bf16 [8][2048][2048]  grid(x=batch,...)
  gemm_bt_kernel<1><<<dim3(8, 16, 16), 256, 0, stream>>>(
      q_bf, keys_bf, scores, 2048, 2048, 1024,
      (long)2048 * 1024, (long)2048 * 1024, (long)2048 * 2048, 0.03125f);
  // softmax rows (masked by valid_lens), in place
  softmax_kernel<<<dim3(B_ * LQ_), 256, 0, stream>>>(scores, valid_lens);
  // GEMM3: out = attn @ values (fp32 epilogue)
  gemm_bt_kernel<2><<<dim3(8, 16, 8), 256, 0, stream>>>(
      scores, valsT, out, 2048, 1024, 2048,
      (long)2048 * 2048, (long)1024 * 2048, (long)2048 * 1024, 1.f);
}

// Round 4
// 447.669 us; speedup vs baseline: 1.2162x; 1.0570x over previous
//
#include <hip/hip_runtime.h>
#include <cstdint>
#include <cstddef>

#define B_   8
#define LQ_  2048
#define LK_  2048

typedef __attribute__((ext_vector_type(8))) __bf16 bf16x8;
typedef __attribute__((ext_vector_type(4))) float f32x4;
typedef __attribute__((ext_vector_type(8))) unsigned short ushortx8;

__device__ __forceinline__ unsigned short f2bf(float f) {
  unsigned u = __builtin_bit_cast(unsigned, f);
  u = u + 0x7fffu + ((u >> 16) & 1u);  // round-to-nearest-even
  return (unsigned short)(u >> 16);
}
__device__ __forceinline__ float bf2f(unsigned short h) {
  unsigned u = ((unsigned)h) << 16;
  return __builtin_bit_cast(float, u);
}

__device__ __forceinline__ void gld_lds16(const void* g, void* l) {
  __builtin_amdgcn_global_load_lds((__attribute__((address_space(1))) void*)(void*)g,
                                   (__attribute__((address_space(3))) void*)l, 16, 0, 0);
}

// ------------- flat cast fp32 -> bf16 for queries+keys in one launch -------------
__global__ __launch_bounds__(256) void cast2_bf16_kernel(
    const float* __restrict__ in0, unsigned short* __restrict__ out0,
    const float* __restrict__ in1, unsigned short* __restrict__ out1,
    size_t half_blocks) {
  const float* in = blockIdx.x < half_blocks ? in0 : in1;
  unsigned short* out = blockIdx.x < half_blocks ? out0 : out1;
  size_t bb = blockIdx.x < half_blocks ? blockIdx.x : blockIdx.x - half_blocks;
  size_t i = (bb * 256 + threadIdx.x) * 8;
  float4 a = *(const float4*)(in + i);
  float4 b = *(const float4*)(in + i + 4);
  ushortx8 o;
  o[0] = f2bf(a.x); o[1] = f2bf(a.y); o[2] = f2bf(a.z); o[3] = f2bf(a.w);
  o[4] = f2bf(b.x); o[5] = f2bf(b.y); o[6] = f2bf(b.z); o[7] = f2bf(b.w);
  *(ushortx8*)(out + i) = o;
}

// ---------------- transpose + cast: fp32 [R][C] -> bf16 [C][R] ----------------
__global__ __launch_bounds__(256) void transpose_cast_kernel(
    const float* __restrict__ in, unsigned short* __restrict__ out,
    int R, int C, long in_bstride, long out_bstride) {
  __shared__ float t[32][33];
  const float* inb = in + (size_t)blockIdx.z * in_bstride;
  unsigned short* outb = out + (size_t)blockIdx.z * out_bstride;
  int c0 = blockIdx.x * 32, r0 = blockIdx.y * 32;
  int tx = threadIdx.x, ty = threadIdx.y;  // block (32,8)
#pragma unroll
  for (int k = 0; k < 4; ++k) {
    int r = ty + k * 8;
    t[r][tx] = inb[(size_t)(r0 + r) * C + c0 + tx];
  }
  __syncthreads();
#pragma unroll
  for (int k = 0; k < 4; ++k) {
    int c = ty + k * 8;
    outb[(size_t)(c0 + c) * R + r0 + tx] = f2bf(t[tx][c]);
  }
}

// ---------------- GEMM: C[M,N] = A[M,K] @ Bt[N,K]^T, BK=64 ----------------
// Grid: (x = N-tile, y = M-tile, z = batch). n-tile rotated by batch so each
// batch spreads over all XCDs (valid_len skipping would otherwise imbalance).
// LDS tiles 128x64 bf16, XOR-swizzled at 16B chunks (pos = chunk ^ (row&7));
// global_load_lds dst is forced base+lane*16, so swizzle inverts the global
// source address.
// OUTM: 0 = bf16, 1 = bf16 scaled, 2 = fp32
// SKIPN: early-exit blocks with n0 >= valid_len (output overwritten by softmax)
// CLAMPK: clamp K-loop to round_up(valid_len,64) (A cols beyond are exact 0)
template <int OUTM, int SKIPN, int CLAMPK>
__global__ __launch_bounds__(256) void gemm_bt_kernel(
    const unsigned short* __restrict__ A, const unsigned short* __restrict__ B,
    void* __restrict__ Cp, int M, int N, int K,
    long a_bstride, long b_bstride, long c_bstride, float scale,
    const int* __restrict__ vlp) {
  __shared__ unsigned short lA[128 * 64];
  __shared__ unsigned short lB[128 * 64];

  const int tid = threadIdx.x;
  const int wave = tid >> 6;
  const int lane = tid & 63;
  const int lane15 = lane & 15;
  const int lhalf = lane >> 4;
  const int nt = (int)((blockIdx.x + 2 * blockIdx.z) & (gridDim.x - 1));
  const int m0 = blockIdx.y * 128;
  const int n0 = nt * 128;

  int vl = K;
  if constexpr (SKIPN || CLAMPK) vl = vlp[blockIdx.z];
  if constexpr (SKIPN) {
    if (n0 >= vl) return;
  }
  int kEnd = K;
  if constexpr (CLAMPK) {
    int ke = (vl + 63) & ~63;
    kEnd = ke < K ? ke : K;
  }

  const int wm = (wave & 1) * 64;
  const int wn = (wave >> 1) * 64;

  const unsigned short* Ab = A + (size_t)blockIdx.z * a_bstride;
  const unsigned short* Bb = B + (size_t)blockIdx.z * b_bstride;

  // staging: 1024 16B-chunks per 128x64 tile, 4 per thread per operand.
  int sr[4], sc[4], sb[4];
#pragma unroll
  for (int j = 0; j < 4; ++j) {
    int blk = (wave * 4 + j) * 64 + lane;
    sb[j] = blk;
    sr[j] = blk >> 3;
    sc[j] = ((blk & 7) ^ ((blk >> 3) & 7)) * 8;
  }

  f32x4 acc[4][4];
#pragma unroll
  for (int i = 0; i < 4; ++i)
#pragma unroll
    for (int j = 0; j < 4; ++j)
      acc[i][j] = (f32x4){0.f, 0.f, 0.f, 0.f};

  const int rswz = lane15 & 7;

  for (int k0 = 0; k0 < kEnd; k0 += 64) {
#pragma unroll
    for (int j = 0; j < 4; ++j)
      gld_lds16(Ab + (size_t)(m0 + sr[j]) * K + (k0 + sc[j]), &lA[sb[j] * 8]);
#pragma unroll
    for (int j = 0; j < 4; ++j)
      gld_lds16(Bb + (size_t)(n0 + sr[j]) * K + (k0 + sc[j]), &lB[sb[j] * 8]);
    __syncthreads();

#pragma unroll
    for (int s = 0; s < 2; ++s) {
      const int cA = ((s * 4 + lhalf) ^ rswz) * 8;
      bf16x8 af[4], bfr[4];
#pragma unroll
      for (int i = 0; i < 4; ++i)
        af[i] = *(const bf16x8*)&lA[(wm + i * 16 + lane15) * 64 + cA];
#pragma unroll
      for (int j = 0; j < 4; ++j)
        bfr[j] = *(const bf16x8*)&lB[(wn + j * 16 + lane15) * 64 + cA];
#pragma unroll
      for (int i = 0; i < 4; ++i)
#pragma unroll
        for (int j = 0; j < 4; ++j)
          acc[i][j] = __builtin_amdgcn_mfma_f32_16x16x32_bf16(af[i], bfr[j], acc[i][j], 0, 0, 0);
    }
    __syncthreads();
  }

  // ---- epilogue: C/D layout col=lane&15, row=(lane>>4)*4+reg ----
  const size_t boffC = (size_t)blockIdx.z * c_bstride;
#pragma unroll
  for (int i = 0; i < 4; ++i) {
    int row = m0 + wm + i * 16 + lhalf * 4;
#pragma unroll
    for (int j = 0; j < 4; ++j) {
      int col = n0 + wn + j * 16 + lane15;
#pragma unroll
      for (int r = 0; r < 4; ++r) {
        float v = acc[i][j][r];
        if constexpr (OUTM == 0) {
          ((unsigned short*)Cp + boffC)[(size_t)(row + r) * N + col] = f2bf(v);
        } else if constexpr (OUTM == 1) {
          ((unsigned short*)Cp + boffC)[(size_t)(row + r) * N + col] = f2bf(v * scale);
        } else {
          ((float*)Cp + boffC)[(size_t)(row + r) * N + col] = v;
        }
      }
    }
  }
}

// ---------------- row softmax with valid_len masking, in-place on bf16 scores ----------------
__global__ __launch_bounds__(256) void softmax_kernel(unsigned short* __restrict__ scores,
                                                      const int* __restrict__ valid_lens) {
  const int row = blockIdx.x;
  const int b = row >> 11;  // LQ = 2048
  const int vl = valid_lens[b];
  unsigned short* rp = scores + (size_t)row * LK_;
  const int tid = threadIdx.x;
  const int wid = tid >> 6, lane = tid & 63;
  __shared__ float sred[4];

  const int cb = tid * 8;
  ushortx8 h = *(const ushortx8*)(rp + cb);
  float x[8];
#pragma unroll
  for (int t = 0; t < 8; ++t) x[t] = bf2f(h[t]);

  float m = -3.4e38f;
#pragma unroll
  for (int t = 0; t < 8; ++t)
    if (cb + t < vl) m = fmaxf(m, x[t]);
#pragma unroll
  for (int off = 32; off >= 1; off >>= 1) m = fmaxf(m, __shfl_xor(m, off));
  if (lane == 0) sred[wid] = m;
  __syncthreads();
  m = fmaxf(fmaxf(sred[0], sred[1]), fmaxf(sred[2], sred[3]));
  __syncthreads();

  float e[8];
  float s = 0.f;
#pragma unroll
  for (int t = 0; t < 8; ++t) {
    e[t] = (cb + t < vl) ? __expf(x[t] - m) : 0.f;
    s += e[t];
  }
#pragma unroll
  for (int off = 32; off >= 1; off >>= 1) s += __shfl_xor(s, off);
  if (lane == 0) sred[wid] = s;
  __syncthreads();
  s = sred[0] + sred[1] + sred[2] + sred[3];
  float inv = 1.f / s;

  ushortx8 o;
#pragma unroll
  for (int t = 0; t < 8; ++t) o[t] = f2bf(e[t] * inv);
  *(ushortx8*)(rp + cb) = o;
}

extern "C" void kernel_launch(void* const* d_in, const int* in_sizes, int n_in,
                              void* d_out, int out_size, void* d_ws, size_t ws_size,
                              hipStream_t stream) {
  const float* queries = (const float*)d_in[0];    // [8,2048,1024]
  const float* keys = (const float*)d_in[1];       // [8,2048,1024]
  const float* values = (const float*)d_in[2];     // [8,2048,1024]
  const int* valid_lens = (const int*)d_in[3];     // [8]
  const float* W_q = (const float*)d_in[4];        // [1024,1024]
  float* out = (float*)d_out;                      // [8,2048,1024] fp32

  // ws layout (ushort elems):
  //   q_bf    [0, 16M)
  //   scores  [16M, 48M)   (qry_bf aliases this region — dead before GEMM2)
  //   valsT   [48M, 64M)
  //   wqT     [64M, 65M)
  //   keys_bf [65M, 81M)        total 162 MiB
  unsigned short* ws = (unsigned short*)d_ws;
  const size_t M1 = (size_t)1024 * 1024;
  unsigned short* q_bf = ws;
  unsigned short* scores = ws + 16 * M1;
  unsigned short* qry_bf = scores;  // alias
  unsigned short* valsT = ws + 48 * M1;
  unsigned short* wqT = ws + 64 * M1;
  unsigned short* keys_bf = ws + 65 * M1;

  // casts: queries + keys, 16M elems each, in one launch
  cast2_bf16_kernel<<<dim3(16384), 256, 0, stream>>>(queries, qry_bf, keys, keys_bf, 8192);
  // WqT[k][d] = W_q[d][k]  (bf16)
  transpose_cast_kernel<<<dim3(32, 32, 1), dim3(32, 8), 0, stream>>>(
      W_q, wqT, 1024, 1024, 0, 0);
  // valsT[b][v][s] = values[b][s][v]  (bf16)
  transpose_cast_kernel<<<dim3(32, 64, 8), dim3(32, 8), 0, stream>>>(
      values, valsT, 2048, 1024, (long)2048 * 1024, (long)1024 * 2048);
  // GEMM1: q = queries @ W_q -> bf16 [16384,1024]   grid(x=Ntiles, y=Mtiles, z=1)
  gemm_bt_kernel<0, 0, 0><<<dim3(8, 128, 1), 256, 0, stream>>>(
      qry_bf, wqT, q_bf, 16384, 1024, 1024, 0, 0, 0, 1.f, nullptr);
  // GEMM2: scores = q @ keys^T / 32 -> bf16 [8][2048][2048]; skip masked N-tiles
  gemm_bt_kernel<1, 1, 0><<<dim3(16, 16, 8), 256, 0, stream>>>(
      q_bf, keys_bf, scores, 2048, 2048, 1024,
      (long)2048 * 1024, (long)2048 * 1024, (long)2048 * 2048, 0.03125f, valid_lens);
  // softmax rows (masked by valid_lens), in place — writes exact 0 for cols>=vl
  softmax_kernel<<<dim3(B_ * LQ_), 256, 0, stream>>>(scores, valid_lens);
  // GEMM3: out = attn @ values (fp32 epilogue); K-loop clamped to valid_len
  gemm_bt_kernel<2, 0, 1><<<dim3(8, 16, 8), 256, 0, stream>>>(
      scores, valsT, out, 2048, 1024, 2048,
      (long)2048 * 2048, (long)1024 * 2048, (long)2048 * 1024, 1.f, valid_lens);
}